// Round 1
// baseline (3486.266 us; speedup 1.0000x reference)
//
#include <hip/hip_runtime.h>

// STAR fused forward, fp32 vector-ALU baseline.
// B=65536 rows, J=8 domains, 512->256->128->64, relu, indicator mix.
// Block = 256 threads, TB=32 rows/block, all domains + layers fused.
// LDS: smemA = H0^T [256][32] (32KB), smemB = weight staging (16KB),
//      smemC = Xs (phase0) / H1^T [128][32] (16KB).  Total 64KB -> 2 blocks/CU.

namespace {
constexpr int D    = 512;
constexpr int H0N  = 256;
constexpr int H1N  = 128;
constexpr int H2N  = 64;
constexpr int NJ   = 8;
constexpr int TB   = 32;
constexpr int NB   = 65536 / TB;   // 2048 blocks

__global__ __launch_bounds__(256, 2) void star_fused(
    const float* __restrict__ x,    // [B,512]
    const float* __restrict__ ind,  // [B,8]
    const float* __restrict__ sk0, const float* __restrict__ sb0,
    const float* __restrict__ dk0, const float* __restrict__ db0,
    const float* __restrict__ sk1, const float* __restrict__ sb1,
    const float* __restrict__ dk1, const float* __restrict__ db1,
    const float* __restrict__ sk2, const float* __restrict__ sb2,
    const float* __restrict__ dk2, const float* __restrict__ db2,
    float* __restrict__ out)        // [B,64]
{
    __shared__ float smemA[H0N * TB];   // 32 KB
    __shared__ float smemB[16 * 256];   // 16 KB
    __shared__ float smemC[128 * TB];   // 16 KB

    const int tid = threadIdx.x;
    const int b0  = blockIdx.x * TB;

    // output mapping: row = tid>>3 (32 rows), cols (tid&7)*8 .. +8
    const int orow = tid >> 3;
    const int ocol = (tid & 7) * 8;

    float oacc[8];
#pragma unroll
    for (int c = 0; c < 8; ++c) oacc[c] = 0.f;

    // phase-0 mapping: 32 col-groups x 8 row-groups; tile 4 rows x 8 cols
    const int cg0 = tid & 31;
    const int rg0 = tid >> 5;
    // phase-1 mapping: 32 col-groups x 8 row-groups; tile 4 rows x 4 cols
    const int cg1 = tid & 31;
    const int rg1 = tid >> 5;

    for (int j = 0; j < NJ; ++j) {
        // ================= phase 0: H0 = relu(X @ (sk0*dk0_j) + b) =========
        float acc0[4][8];
#pragma unroll
        for (int r = 0; r < 4; ++r)
#pragma unroll
            for (int c = 0; c < 8; ++c) acc0[r][c] = 0.f;

        for (int kb = 0; kb < D; kb += 16) {
            // stage Xs[16][32] into smemC (transposed: k-major)
            if (tid < 128) {
                const int r  = tid >> 2;
                const int k0 = (tid & 3) * 4;
                const float4 xv = *reinterpret_cast<const float4*>(
                    x + (size_t)(b0 + r) * D + kb + k0);
                smemC[(k0 + 0) * TB + r] = xv.x;
                smemC[(k0 + 1) * TB + r] = xv.y;
                smemC[(k0 + 2) * TB + r] = xv.z;
                smemC[(k0 + 3) * TB + r] = xv.w;
            }
            // stage Ws[16][256] = sk0*dk0_j chunk into smemB
            {
                const int k  = tid >> 4;          // 0..15
                const int o0 = (tid & 15) * 4;    // + 64*q
                const float* skp = sk0 + (size_t)(kb + k) * H0N;
                const float* dkp = dk0 + ((size_t)j * D + kb + k) * H0N;
#pragma unroll
                for (int q = 0; q < 4; ++q) {
                    const int o = o0 + 64 * q;
                    const float4 s = *reinterpret_cast<const float4*>(skp + o);
                    const float4 d = *reinterpret_cast<const float4*>(dkp + o);
                    float4 w;
                    w.x = s.x * d.x; w.y = s.y * d.y;
                    w.z = s.z * d.z; w.w = s.w * d.w;
                    *reinterpret_cast<float4*>(&smemB[k * H0N + o]) = w;
                }
            }
            __syncthreads();
#pragma unroll
            for (int k = 0; k < 16; ++k) {
                const float4 xa  = *reinterpret_cast<const float4*>(&smemC[k * TB + rg0 * 4]);
                const float4 wb0 = *reinterpret_cast<const float4*>(&smemB[k * H0N + cg0 * 8]);
                const float4 wb1 = *reinterpret_cast<const float4*>(&smemB[k * H0N + cg0 * 8 + 4]);
                const float xr[4] = {xa.x, xa.y, xa.z, xa.w};
                const float wc[8] = {wb0.x, wb0.y, wb0.z, wb0.w,
                                     wb1.x, wb1.y, wb1.z, wb1.w};
#pragma unroll
                for (int r = 0; r < 4; ++r)
#pragma unroll
                    for (int c = 0; c < 8; ++c)
                        acc0[r][c] = fmaf(xr[r], wc[c], acc0[r][c]);
            }
            __syncthreads();
        }
        // epilogue 0: bias + relu -> smemA = H0^T [256][32]
        {
            const float4 s0 = *reinterpret_cast<const float4*>(sb0 + cg0 * 8);
            const float4 s1 = *reinterpret_cast<const float4*>(sb0 + cg0 * 8 + 4);
            const float4 d0 = *reinterpret_cast<const float4*>(db0 + (size_t)j * H0N + cg0 * 8);
            const float4 d1 = *reinterpret_cast<const float4*>(db0 + (size_t)j * H0N + cg0 * 8 + 4);
            const float bias[8] = {s0.x + d0.x, s0.y + d0.y, s0.z + d0.z, s0.w + d0.w,
                                   s1.x + d1.x, s1.y + d1.y, s1.z + d1.z, s1.w + d1.w};
#pragma unroll
            for (int c = 0; c < 8; ++c)
#pragma unroll
                for (int r = 0; r < 4; ++r) {
                    float v = acc0[r][c] + bias[c];
                    v = fmaxf(v, 0.f);
                    smemA[(cg0 * 8 + c) * TB + rg0 * 4 + r] = v;
                }
        }
        __syncthreads();

        // ================= phase 1: H1 = relu(H0 @ (sk1*dk1_j) + b) ========
        float acc1[4][4];
#pragma unroll
        for (int r = 0; r < 4; ++r)
#pragma unroll
            for (int c = 0; c < 4; ++c) acc1[r][c] = 0.f;

        for (int kb = 0; kb < H0N; kb += 32) {
            // stage Ws1 [32][128]
            {
                const int kA = tid >> 4;          // 0..15
                const int o0 = (tid & 15) * 4;    // + 64*q
#pragma unroll
                for (int kq = 0; kq < 2; ++kq) {
                    const int k = kA + 16 * kq;
                    const float* skp = sk1 + (size_t)(kb + k) * H1N;
                    const float* dkp = dk1 + ((size_t)j * H0N + kb + k) * H1N;
#pragma unroll
                    for (int q = 0; q < 2; ++q) {
                        const int o = o0 + 64 * q;
                        const float4 s = *reinterpret_cast<const float4*>(skp + o);
                        const float4 d = *reinterpret_cast<const float4*>(dkp + o);
                        float4 w;
                        w.x = s.x * d.x; w.y = s.y * d.y;
                        w.z = s.z * d.z; w.w = s.w * d.w;
                        *reinterpret_cast<float4*>(&smemB[k * H1N + o]) = w;
                    }
                }
            }
            __syncthreads();
#pragma unroll
            for (int k = 0; k < 32; ++k) {
                const float4 ha = *reinterpret_cast<const float4*>(&smemA[(kb + k) * TB + rg1 * 4]);
                const float4 wb = *reinterpret_cast<const float4*>(&smemB[k * H1N + cg1 * 4]);
                const float hr[4] = {ha.x, ha.y, ha.z, ha.w};
                const float wc[4] = {wb.x, wb.y, wb.z, wb.w};
#pragma unroll
                for (int r = 0; r < 4; ++r)
#pragma unroll
                    for (int c = 0; c < 4; ++c)
                        acc1[r][c] = fmaf(hr[r], wc[c], acc1[r][c]);
            }
            __syncthreads();
        }
        // epilogue 1: bias + relu -> smemC = H1^T [128][32]
        {
            const float4 s0 = *reinterpret_cast<const float4*>(sb1 + cg1 * 4);
            const float4 d0 = *reinterpret_cast<const float4*>(db1 + (size_t)j * H1N + cg1 * 4);
            const float bias[4] = {s0.x + d0.x, s0.y + d0.y, s0.z + d0.z, s0.w + d0.w};
#pragma unroll
            for (int c = 0; c < 4; ++c)
#pragma unroll
                for (int r = 0; r < 4; ++r) {
                    float v = acc1[r][c] + bias[c];
                    v = fmaxf(v, 0.f);
                    smemC[(cg1 * 4 + c) * TB + rg1 * 4 + r] = v;
                }
        }
        __syncthreads();

        // ================= phase 2: H2 = relu(H1 @ (sk2*dk2_j) + b), mix ===
        float acc2[8];
#pragma unroll
        for (int c = 0; c < 8; ++c) acc2[c] = 0.f;

        for (int kb = 0; kb < H1N; kb += 64) {
            // stage Ws2 [64][64]
            {
                const int o0 = (tid & 15) * 4;
#pragma unroll
                for (int q = 0; q < 4; ++q) {
                    const int k = (tid >> 4) + 16 * q;
                    const float* skp = sk2 + (size_t)(kb + k) * H2N;
                    const float* dkp = dk2 + ((size_t)j * H1N + kb + k) * H2N;
                    const float4 s = *reinterpret_cast<const float4*>(skp + o0);
                    const float4 d = *reinterpret_cast<const float4*>(dkp + o0);
                    float4 w;
                    w.x = s.x * d.x; w.y = s.y * d.y;
                    w.z = s.z * d.z; w.w = s.w * d.w;
                    *reinterpret_cast<float4*>(&smemB[k * H2N + o0]) = w;
                }
            }
            __syncthreads();
#pragma unroll
            for (int k = 0; k < 64; ++k) {
                const float hv = smemC[(kb + k) * TB + orow];
                const float4 w0 = *reinterpret_cast<const float4*>(&smemB[k * H2N + ocol]);
                const float4 w1 = *reinterpret_cast<const float4*>(&smemB[k * H2N + ocol + 4]);
                acc2[0] = fmaf(hv, w0.x, acc2[0]);
                acc2[1] = fmaf(hv, w0.y, acc2[1]);
                acc2[2] = fmaf(hv, w0.z, acc2[2]);
                acc2[3] = fmaf(hv, w0.w, acc2[3]);
                acc2[4] = fmaf(hv, w1.x, acc2[4]);
                acc2[5] = fmaf(hv, w1.y, acc2[5]);
                acc2[6] = fmaf(hv, w1.z, acc2[6]);
                acc2[7] = fmaf(hv, w1.w, acc2[7]);
            }
            __syncthreads();
        }
        // epilogue 2: bias + relu + indicator mix (registers)
        {
            const float indv = ind[(size_t)(b0 + orow) * NJ + j];
            const float4 s0 = *reinterpret_cast<const float4*>(sb2 + ocol);
            const float4 s1 = *reinterpret_cast<const float4*>(sb2 + ocol + 4);
            const float4 d0 = *reinterpret_cast<const float4*>(db2 + (size_t)j * H2N + ocol);
            const float4 d1 = *reinterpret_cast<const float4*>(db2 + (size_t)j * H2N + ocol + 4);
            const float bias[8] = {s0.x + d0.x, s0.y + d0.y, s0.z + d0.z, s0.w + d0.w,
                                   s1.x + d1.x, s1.y + d1.y, s1.z + d1.z, s1.w + d1.w};
#pragma unroll
            for (int c = 0; c < 8; ++c) {
                float v = acc2[c] + bias[c];
                v = fmaxf(v, 0.f);
                oacc[c] = fmaf(indv, v, oacc[c]);
            }
        }
        // trailing __syncthreads of the phase-2 k-loop already ordered all
        // LDS reads before next j's staging writes.
    }

    // final coalesced store: out[b0+orow][ocol..ocol+8)
    float4 o0v, o1v;
    o0v.x = oacc[0]; o0v.y = oacc[1]; o0v.z = oacc[2]; o0v.w = oacc[3];
    o1v.x = oacc[4]; o1v.y = oacc[5]; o1v.z = oacc[6]; o1v.w = oacc[7];
    float* op = out + (size_t)(b0 + orow) * H2N + ocol;
    *reinterpret_cast<float4*>(op)     = o0v;
    *reinterpret_cast<float4*>(op + 4) = o1v;
}
} // namespace

extern "C" void kernel_launch(void* const* d_in, const int* in_sizes, int n_in,
                              void* d_out, int out_size, void* d_ws, size_t ws_size,
                              hipStream_t stream) {
    const float* x   = (const float*)d_in[0];
    const float* ind = (const float*)d_in[1];
    const float* sk0 = (const float*)d_in[2];
    const float* sb0 = (const float*)d_in[3];
    const float* dk0 = (const float*)d_in[4];
    const float* db0 = (const float*)d_in[5];
    const float* sk1 = (const float*)d_in[6];
    const float* sb1 = (const float*)d_in[7];
    const float* dk1 = (const float*)d_in[8];
    const float* db1 = (const float*)d_in[9];
    const float* sk2 = (const float*)d_in[10];
    const float* sb2 = (const float*)d_in[11];
    const float* dk2 = (const float*)d_in[12];
    const float* db2 = (const float*)d_in[13];
    float* out = (float*)d_out;

    star_fused<<<dim3(NB), dim3(256), 0, stream>>>(
        x, ind, sk0, sb0, dk0, db0, sk1, sb1, dk1, db1, sk2, sb2, dk2, db2, out);
}

// Round 2
// 1008.854 us; speedup vs baseline: 3.4557x; 3.4557x over previous
//
#include <hip/hip_runtime.h>
#include <stdint.h>

// STAR fused forward via split-precision bf16x2 MFMA (gfx950).
// acc = Ahi*Bhi + Ahi*Blo + Alo*Bhi  (fp32 MFMA accumulate) -> ~2^-16 rel err.
// prep kernel: fuses w = sk*dk, splits to hi/lo bf16 planes in MFMA B-frag
// order (lane-contiguous 16B per lane), and fuses biases. Main kernel reads
// B-frags straight from ws (L2) with coalesced dwordx4 - no LDS staging, no
// barriers in K-loops. H0/H1 transposes go through LDS as packed hi|lo u32.

namespace {

typedef __attribute__((ext_vector_type(8))) short bf16x8;
typedef __attribute__((ext_vector_type(4))) float f32x4;

union Frag { bf16x8 v; unsigned int u[4]; };

// ws byte layout
constexpr size_t WS_L0   = 0;                 // 8j*16kc*16nt pairs * 2048B = 4 MiB
constexpr size_t WS_L1   = 4194304;           // 8*8*8 pairs  * 2048B = 1 MiB
constexpr size_t WS_L2   = 5242880;           // 8*4*4 pairs  * 2048B = 256 KiB
constexpr size_t WS_B0   = 5505024;           // 8*256 f32
constexpr size_t WS_B1   = 5513216;           // 8*128 f32
constexpr size_t WS_B2   = 5517312;           // 8*64  f32
// total 5519360 B (~5.3 MiB) of d_ws used.

constexpr int PREP_TOTAL = 1048576 + 262144 + 65536 + 2048 + 1024 + 512; // 1379840

__device__ __forceinline__ void splitpair(float a, float b,
                                          unsigned int& hi, unsigned int& lo) {
    unsigned int ua = __float_as_uint(a);
    unsigned int ub = __float_as_uint(b);
    unsigned int ha = ua & 0xffff0000u;
    unsigned int hb = ub & 0xffff0000u;
    float ra = a - __uint_as_float(ha);
    float rb = b - __uint_as_float(hb);
    hi = (ua >> 16) | hb;
    lo = (__float_as_uint(ra) >> 16) | (__float_as_uint(rb) & 0xffff0000u);
}

__device__ __forceinline__ unsigned int packsplit(float v) {
    unsigned int u = __float_as_uint(v);
    unsigned int h = u & 0xffff0000u;
    float r = v - __uint_as_float(h);
    return h | (__float_as_uint(r) >> 16);
}

__device__ __forceinline__ void unpack2(unsigned int e0, unsigned int e1,
                                        unsigned int& hi, unsigned int& lo) {
    hi = (e0 >> 16) | (e1 & 0xffff0000u);
    lo = (e0 & 0xffffu) | (e1 << 16);
}

// ---------------- prep: fuse sk*dk -> hi/lo bf16 frag-order planes + biases
__global__ void prep_ws(const float* __restrict__ sk0, const float* __restrict__ dk0,
                        const float* __restrict__ sk1, const float* __restrict__ dk1,
                        const float* __restrict__ sk2, const float* __restrict__ dk2,
                        const float* __restrict__ sb0, const float* __restrict__ db0,
                        const float* __restrict__ sb1, const float* __restrict__ db1,
                        const float* __restrict__ sb2, const float* __restrict__ db2,
                        char* __restrict__ ws) {
    int tid = blockIdx.x * 256 + threadIdx.x;
    if (tid < 1048576) {                       // layer 0: [j][k<512][n<256]
        int n = tid & 255, k = (tid >> 8) & 511, j = tid >> 17;
        float wv = sk0[k * 256 + n] * dk0[(size_t)(j * 512 + k) * 256 + n];
        unsigned int u = __float_as_uint(wv);
        unsigned int h = u & 0xffff0000u;
        float r = wv - __uint_as_float(h);
        int pair = (j * 16 + (k >> 5)) * 16 + (n >> 4);
        int lane = (n & 15) | (((k >> 3) & 3) << 4);
        size_t off = WS_L0 + (size_t)pair * 2048 + lane * 16 + (k & 7) * 2;
        *(unsigned short*)(ws + off)        = (unsigned short)(u >> 16);
        *(unsigned short*)(ws + off + 1024) = (unsigned short)(__float_as_uint(r) >> 16);
    } else if (tid < 1310720) {                // layer 1: [j][k<256][n<128]
        int t = tid - 1048576;
        int n = t & 127, k = (t >> 7) & 255, j = t >> 15;
        float wv = sk1[k * 128 + n] * dk1[(size_t)(j * 256 + k) * 128 + n];
        unsigned int u = __float_as_uint(wv);
        unsigned int h = u & 0xffff0000u;
        float r = wv - __uint_as_float(h);
        int pair = (j * 8 + (k >> 5)) * 8 + (n >> 4);
        int lane = (n & 15) | (((k >> 3) & 3) << 4);
        size_t off = WS_L1 + (size_t)pair * 2048 + lane * 16 + (k & 7) * 2;
        *(unsigned short*)(ws + off)        = (unsigned short)(u >> 16);
        *(unsigned short*)(ws + off + 1024) = (unsigned short)(__float_as_uint(r) >> 16);
    } else if (tid < 1376256) {                // layer 2: [j][k<128][n<64]
        int t = tid - 1310720;
        int n = t & 63, k = (t >> 6) & 127, j = t >> 13;
        float wv = sk2[k * 64 + n] * dk2[(size_t)(j * 128 + k) * 64 + n];
        unsigned int u = __float_as_uint(wv);
        unsigned int h = u & 0xffff0000u;
        float r = wv - __uint_as_float(h);
        int pair = (j * 4 + (k >> 5)) * 4 + (n >> 4);
        int lane = (n & 15) | (((k >> 3) & 3) << 4);
        size_t off = WS_L2 + (size_t)pair * 2048 + lane * 16 + (k & 7) * 2;
        *(unsigned short*)(ws + off)        = (unsigned short)(u >> 16);
        *(unsigned short*)(ws + off + 1024) = (unsigned short)(__float_as_uint(r) >> 16);
    } else if (tid < 1378304) {                // bias0: 8*256
        int t = tid - 1376256;
        ((float*)(ws + WS_B0))[t] = sb0[t & 255] + db0[t];
    } else if (tid < 1379328) {                // bias1: 8*128
        int t = tid - 1378304;
        ((float*)(ws + WS_B1))[t] = sb1[t & 127] + db1[t];
    } else if (tid < PREP_TOTAL) {             // bias2: 8*64
        int t = tid - 1379328;
        ((float*)(ws + WS_B2))[t] = sb2[t & 63] + db2[t];
    }
}

// ---------------- main kernel: 256 thr (4 waves), 32 rows/block, 2048 blocks
__global__ __launch_bounds__(256, 3) void star_mfma(
    const float* __restrict__ x,    // [65536,512]
    const float* __restrict__ ind,  // [65536,8]
    const char* __restrict__ ws,
    float* __restrict__ out)        // [65536,64]
{
    __shared__ unsigned int H0s[32 * 260];  // packed hi|lo, [m][k], pad +4
    __shared__ unsigned int H1s[32 * 132];
    __shared__ float indS[8 * 33];

    const int tid  = threadIdx.x;
    const int w    = tid >> 6;      // wave 0..3 (n-split in every phase)
    const int lane = tid & 63;
    const int c    = lane & 15;
    const int q    = lane >> 4;
    const int b0   = blockIdx.x * 32;

    const char* wB0 = ws + WS_L0;
    const char* wB1 = ws + WS_L1;
    const char* wB2 = ws + WS_L2;
    const float* bias0 = (const float*)(ws + WS_B0);
    const float* bias1 = (const float*)(ws + WS_B1);
    const float* bias2 = (const float*)(ws + WS_B2);

    // stage indicator (transposed, padded): indS[j][m]
    indS[(tid & 7) * 33 + (tid >> 3)] = ind[(size_t)b0 * 8 + tid];

    const f32x4 z = {0.f, 0.f, 0.f, 0.f};
    f32x4 oacc[2]; oacc[0] = z; oacc[1] = z;

    __syncthreads();

    for (int j = 0; j < 8; ++j) {
        // ================= phase 0: X[32,512] @ W0[512,256] ================
        f32x4 acc0[2][4];
#pragma unroll
        for (int mt = 0; mt < 2; ++mt)
#pragma unroll
            for (int ntl = 0; ntl < 4; ++ntl) acc0[mt][ntl] = z;

        for (int kc = 0; kc < 16; ++kc) {
            Frag Ahi[2], Alo[2];
#pragma unroll
            for (int mt = 0; mt < 2; ++mt) {
                const float* ap = x + (size_t)(b0 + mt * 16 + c) * 512 + kc * 32 + q * 8;
                float4 a0 = *(const float4*)ap;
                float4 a1 = *(const float4*)(ap + 4);
                splitpair(a0.x, a0.y, Ahi[mt].u[0], Alo[mt].u[0]);
                splitpair(a0.z, a0.w, Ahi[mt].u[1], Alo[mt].u[1]);
                splitpair(a1.x, a1.y, Ahi[mt].u[2], Alo[mt].u[2]);
                splitpair(a1.z, a1.w, Ahi[mt].u[3], Alo[mt].u[3]);
            }
#pragma unroll
            for (int ntl = 0; ntl < 4; ++ntl) {
                const int nt = w * 4 + ntl;
                const char* pb = wB0 + ((size_t)((j * 16 + kc) * 16 + nt) * 2048) + lane * 16;
                Frag Bhi, Blo;
                *(uint4*)Bhi.u = *(const uint4*)pb;
                *(uint4*)Blo.u = *(const uint4*)(pb + 1024);
#pragma unroll
                for (int mt = 0; mt < 2; ++mt) {
                    acc0[mt][ntl] = __builtin_amdgcn_mfma_f32_16x16x32_bf16(Ahi[mt].v, Bhi.v, acc0[mt][ntl], 0, 0, 0);
                    acc0[mt][ntl] = __builtin_amdgcn_mfma_f32_16x16x32_bf16(Ahi[mt].v, Blo.v, acc0[mt][ntl], 0, 0, 0);
                    acc0[mt][ntl] = __builtin_amdgcn_mfma_f32_16x16x32_bf16(Alo[mt].v, Bhi.v, acc0[mt][ntl], 0, 0, 0);
                }
            }
        }
        // epilogue 0: bias + relu -> packed split into H0s[m][k], k = H0 col
#pragma unroll
        for (int ntl = 0; ntl < 4; ++ntl) {
            const float bv = bias0[j * 256 + w * 64 + ntl * 16 + c];
#pragma unroll
            for (int mt = 0; mt < 2; ++mt)
#pragma unroll
                for (int r = 0; r < 4; ++r) {
                    float v = acc0[mt][ntl][r] + bv;
                    v = fmaxf(v, 0.f);
                    H0s[(mt * 16 + q * 4 + r) * 260 + w * 64 + ntl * 16 + c] = packsplit(v);
                }
        }
        __syncthreads();

        // ================= phase 1: H0[32,256] @ W1[256,128] ===============
        f32x4 acc1[2][2];
#pragma unroll
        for (int mt = 0; mt < 2; ++mt)
#pragma unroll
            for (int ntl = 0; ntl < 2; ++ntl) acc1[mt][ntl] = z;

        for (int kc = 0; kc < 8; ++kc) {
            Frag Ahi[2], Alo[2];
#pragma unroll
            for (int mt = 0; mt < 2; ++mt) {
                const unsigned int* hp = &H0s[(mt * 16 + c) * 260 + kc * 32 + q * 8];
                uint4 e0 = *(const uint4*)hp;
                uint4 e1 = *(const uint4*)(hp + 4);
                unpack2(e0.x, e0.y, Ahi[mt].u[0], Alo[mt].u[0]);
                unpack2(e0.z, e0.w, Ahi[mt].u[1], Alo[mt].u[1]);
                unpack2(e1.x, e1.y, Ahi[mt].u[2], Alo[mt].u[2]);
                unpack2(e1.z, e1.w, Ahi[mt].u[3], Alo[mt].u[3]);
            }
#pragma unroll
            for (int ntl = 0; ntl < 2; ++ntl) {
                const int nt = w * 2 + ntl;
                const char* pb = wB1 + ((size_t)((j * 8 + kc) * 8 + nt) * 2048) + lane * 16;
                Frag Bhi, Blo;
                *(uint4*)Bhi.u = *(const uint4*)pb;
                *(uint4*)Blo.u = *(const uint4*)(pb + 1024);
#pragma unroll
                for (int mt = 0; mt < 2; ++mt) {
                    acc1[mt][ntl] = __builtin_amdgcn_mfma_f32_16x16x32_bf16(Ahi[mt].v, Bhi.v, acc1[mt][ntl], 0, 0, 0);
                    acc1[mt][ntl] = __builtin_amdgcn_mfma_f32_16x16x32_bf16(Ahi[mt].v, Blo.v, acc1[mt][ntl], 0, 0, 0);
                    acc1[mt][ntl] = __builtin_amdgcn_mfma_f32_16x16x32_bf16(Alo[mt].v, Bhi.v, acc1[mt][ntl], 0, 0, 0);
                }
            }
        }
        // epilogue 1 -> H1s
#pragma unroll
        for (int ntl = 0; ntl < 2; ++ntl) {
            const float bv = bias1[j * 128 + w * 32 + ntl * 16 + c];
#pragma unroll
            for (int mt = 0; mt < 2; ++mt)
#pragma unroll
                for (int r = 0; r < 4; ++r) {
                    float v = acc1[mt][ntl][r] + bv;
                    v = fmaxf(v, 0.f);
                    H1s[(mt * 16 + q * 4 + r) * 132 + w * 32 + ntl * 16 + c] = packsplit(v);
                }
        }
        __syncthreads();

        // ================= phase 2: H1[32,128] @ W2[128,64], mix ==========
        f32x4 acc2[2]; acc2[0] = z; acc2[1] = z;

        for (int kc = 0; kc < 4; ++kc) {
            Frag Ahi[2], Alo[2];
#pragma unroll
            for (int mt = 0; mt < 2; ++mt) {
                const unsigned int* hp = &H1s[(mt * 16 + c) * 132 + kc * 32 + q * 8];
                uint4 e0 = *(const uint4*)hp;
                uint4 e1 = *(const uint4*)(hp + 4);
                unpack2(e0.x, e0.y, Ahi[mt].u[0], Alo[mt].u[0]);
                unpack2(e0.z, e0.w, Ahi[mt].u[1], Alo[mt].u[1]);
                unpack2(e1.x, e1.y, Ahi[mt].u[2], Alo[mt].u[2]);
                unpack2(e1.z, e1.w, Ahi[mt].u[3], Alo[mt].u[3]);
            }
            const char* pb = wB2 + ((size_t)((j * 4 + kc) * 4 + w) * 2048) + lane * 16;
            Frag Bhi, Blo;
            *(uint4*)Bhi.u = *(const uint4*)pb;
            *(uint4*)Blo.u = *(const uint4*)(pb + 1024);
#pragma unroll
            for (int mt = 0; mt < 2; ++mt) {
                acc2[mt] = __builtin_amdgcn_mfma_f32_16x16x32_bf16(Ahi[mt].v, Bhi.v, acc2[mt], 0, 0, 0);
                acc2[mt] = __builtin_amdgcn_mfma_f32_16x16x32_bf16(Ahi[mt].v, Blo.v, acc2[mt], 0, 0, 0);
                acc2[mt] = __builtin_amdgcn_mfma_f32_16x16x32_bf16(Alo[mt].v, Bhi.v, acc2[mt], 0, 0, 0);
            }
        }
        // epilogue 2: bias + relu + indicator mix into oacc (registers)
        {
            const float bv = bias2[j * 64 + w * 16 + c];
#pragma unroll
            for (int mt = 0; mt < 2; ++mt)
#pragma unroll
                for (int r = 0; r < 4; ++r) {
                    float v = acc2[mt][r] + bv;
                    v = fmaxf(v, 0.f);
                    oacc[mt][r] = fmaf(indS[j * 33 + mt * 16 + q * 4 + r], v, oacc[mt][r]);
                }
        }
        // H0/H1 hazards vs next j are covered by the two barriers above.
    }

    // store: out[b0 + m][w*16 + c]
#pragma unroll
    for (int mt = 0; mt < 2; ++mt)
#pragma unroll
        for (int r = 0; r < 4; ++r)
            out[(size_t)(b0 + mt * 16 + q * 4 + r) * 64 + w * 16 + c] = oacc[mt][r];
}

} // namespace

extern "C" void kernel_launch(void* const* d_in, const int* in_sizes, int n_in,
                              void* d_out, int out_size, void* d_ws, size_t ws_size,
                              hipStream_t stream) {
    const float* x   = (const float*)d_in[0];
    const float* ind = (const float*)d_in[1];
    const float* sk0 = (const float*)d_in[2];
    const float* sb0 = (const float*)d_in[3];
    const float* dk0 = (const float*)d_in[4];
    const float* db0 = (const float*)d_in[5];
    const float* sk1 = (const float*)d_in[6];
    const float* sb1 = (const float*)d_in[7];
    const float* dk1 = (const float*)d_in[8];
    const float* db1 = (const float*)d_in[9];
    const float* sk2 = (const float*)d_in[10];
    const float* sb2 = (const float*)d_in[11];
    const float* dk2 = (const float*)d_in[12];
    const float* db2 = (const float*)d_in[13];
    char* ws   = (char*)d_ws;      // needs ~5.3 MiB
    float* out = (float*)d_out;

    prep_ws<<<dim3((PREP_TOTAL + 255) / 256), dim3(256), 0, stream>>>(
        sk0, dk0, sk1, dk1, sk2, dk2, sb0, db0, sb1, db1, sb2, db2, ws);

    star_mfma<<<dim3(2048), dim3(256), 0, stream>>>(x, ind, ws, out);
}